// Round 1
// baseline (412.981 us; speedup 1.0000x reference)
//
#include <hip/hip_runtime.h>

// ---------------------------------------------------------------------------
// MultiHeadSelfAttention: B=4 S=2048 D=1024 H=16 DK=64, RoPE, causal, out-proj
// Round 0: f16 MFMA pipeline.
//   cvt(x,w*) -> rope tables -> QKV gemm (+RoPE epilogue, V transposed)
//   -> flash attention -> out gemm (f32)
// ---------------------------------------------------------------------------

typedef _Float16 f16;
typedef _Float16 f16x4 __attribute__((ext_vector_type(4)));
typedef _Float16 f16x8 __attribute__((ext_vector_type(8)));
typedef float    f32x4 __attribute__((ext_vector_type(4)));

typedef __attribute__((address_space(1))) void gvoid_t;
typedef __attribute__((address_space(3))) void lvoid_t;

// async global->LDS, 16B per lane; LDS dest = wave-uniform base + lane*16
#define GLD16(g, l) __builtin_amdgcn_global_load_lds( \
    (gvoid_t*)(const void*)(g), (lvoid_t*)(l), 16, 0, 0)

constexpr int BB = 4, SS = 2048, DD = 1024, HH = 16, DKK = 64;
constexpr int MM = BB * SS;  // 8192

// ---------------- f32 -> f16 convert (vectorized) ----------------
__global__ void cvt_kernel(const float4* __restrict__ in, f16x4* __restrict__ out, int n4) {
    int stride = gridDim.x * blockDim.x;
    for (int i = blockIdx.x * blockDim.x + threadIdx.x; i < n4; i += stride) {
        float4 v = in[i];
        f16x4 o;
        o[0] = (f16)v.x; o[1] = (f16)v.y; o[2] = (f16)v.z; o[3] = (f16)v.w;
        out[i] = o;
    }
}

// ---------------- RoPE tables: ctab/stab[s][dk] = cos/sin(s * invfreq[dk>>1])
__global__ void rope_tab_kernel(float* __restrict__ ctab, float* __restrict__ stab) {
    int idx = blockIdx.x * blockDim.x + threadIdx.x;
    if (idx >= SS * DKK) return;
    int s = idx >> 6, dk = idx & 63, i = dk >> 1;
    float inv = powf(10000.0f, -(float)(2 * i) / (float)DKK);
    float ang = (float)s * inv;
    ctab[idx] = cosf(ang);
    stab[idx] = sinf(ang);
}

// ---------------- GEMM core: C[128x128] tile, A[M][K], B-as-[N][K], K=1024 ---
// m97 structure: BK=32, global_load_lds staging, 16x16x32 f16 MFMA, 4 waves 2x2.
__device__ __forceinline__ void gemm_core(
    const f16* __restrict__ A, const f16* __restrict__ Bm,
    f16* As, f16* Bs, f32x4 (&acc)[4][4], int bm, int bn)
{
    const int tid  = threadIdx.x;
    const int lane = tid & 63, wid = tid >> 6;
    const int lrow = lane & 15, lk = lane >> 4;
    const int wm = (wid >> 1) * 64, wn = (wid & 1) * 64;
    // staging chunks: 512 x 16B per tile; thread loads 2 per matrix
    const int ci0 = wid * 64 + lane;
    const int ci1 = (4 + wid) * 64 + lane;
    const int r0 = ci0 >> 2, c0 = (ci0 & 3) * 8;
    const int r1 = ci1 >> 2, c1 = (ci1 & 3) * 8;

    for (int k0 = 0; k0 < 1024; k0 += 32) {
        GLD16(A  + (size_t)(bm + r0) * 1024 + k0 + c0, As + wid * 512);
        GLD16(A  + (size_t)(bm + r1) * 1024 + k0 + c1, As + (4 + wid) * 512);
        GLD16(Bm + (size_t)(bn + r0) * 1024 + k0 + c0, Bs + wid * 512);
        GLD16(Bm + (size_t)(bn + r1) * 1024 + k0 + c1, Bs + (4 + wid) * 512);
        __syncthreads();
        f16x8 af[4], bf[4];
#pragma unroll
        for (int mi = 0; mi < 4; ++mi)
            af[mi] = *(const f16x8*)&As[(wm + mi * 16 + lrow) * 32 + lk * 8];
#pragma unroll
        for (int ni = 0; ni < 4; ++ni)
            bf[ni] = *(const f16x8*)&Bs[(wn + ni * 16 + lrow) * 32 + lk * 8];
#pragma unroll
        for (int mi = 0; mi < 4; ++mi)
#pragma unroll
            for (int ni = 0; ni < 4; ++ni)
                acc[mi][ni] = __builtin_amdgcn_mfma_f32_16x16x32_f16(
                    af[mi], bf[ni], acc[mi][ni], 0, 0, 0);
        __syncthreads();
    }
}

// ---------------- QKV GEMM + RoPE epilogue; z: 0=Q 1=K 2=V ----------------
__global__ __launch_bounds__(256) void qkv_gemm(
    const f16* __restrict__ xb,
    const f16* __restrict__ wqb, const f16* __restrict__ wkb, const f16* __restrict__ wvb,
    f16* __restrict__ Qr, f16* __restrict__ Kr, f16* __restrict__ Vt,
    const float* __restrict__ ctab, const float* __restrict__ stab)
{
    __shared__ __align__(16) f16 As[128 * 32];
    __shared__ __align__(16) f16 Bs[128 * 32];
    const int z = blockIdx.z;
    const f16* Bm = (z == 0) ? wqb : (z == 1) ? wkb : wvb;
    const int bm = blockIdx.y * 128, bn = blockIdx.x * 128;
    f32x4 acc[4][4] = {};
    gemm_core(xb, Bm, As, Bs, acc, bm, bn);

    const int tid = threadIdx.x, lane = tid & 63, wid = tid >> 6;
    const int lrow = lane & 15, lk = lane >> 4;
    const int wm = (wid >> 1) * 64, wn = (wid & 1) * 64;

    if (z == 2) {
        // V stored transposed: [b,h,dk,s] so attention stages Vt rows directly
#pragma unroll
        for (int mi = 0; mi < 4; ++mi)
#pragma unroll
            for (int ni = 0; ni < 4; ++ni)
#pragma unroll
                for (int r = 0; r < 4; ++r) {
                    int row = bm + wm + mi * 16 + lk * 4 + r;   // (b,s)
                    int col = bn + wn + ni * 16 + lrow;          // (h,dk)
                    int b = row >> 11, s = row & 2047, h = col >> 6, dk = col & 63;
                    Vt[((size_t)(b * HH + h) * DKK + dk) * SS + s] = (f16)acc[mi][ni][r];
                }
    } else {
        f16* Out = (z == 0) ? Qr : Kr;
        const float scale = (z == 0) ? 0.125f : 1.0f;  // fold 1/sqrt(DK) into Q
#pragma unroll
        for (int mi = 0; mi < 4; ++mi)
#pragma unroll
            for (int ni = 0; ni < 4; ++ni)
#pragma unroll
                for (int r = 0; r < 4; ++r) {
                    int row = bm + wm + mi * 16 + lk * 4 + r;
                    int col = bn + wn + ni * 16 + lrow;
                    int b = row >> 11, s = row & 2047, h = col >> 6, dk = col & 63;
                    float v = acc[mi][ni][r];
                    float partner = __shfl_xor(v, 1);   // adjacent column (same rows)
                    float cc = ctab[s * DKK + dk], ssn = stab[s * DKK + dk];
                    float rot = (col & 1) ? partner : -partner;
                    float o = (v * cc + rot * ssn) * scale;
                    Out[((size_t)(b * HH + h) * SS + s) * DKK + dk] = (f16)o;
                }
    }
}

// ---------------- Flash attention: per (b,h), 128 q-rows/block, KV tiles of 64
__global__ __launch_bounds__(256) void attn_kernel(
    const f16* __restrict__ Q, const f16* __restrict__ K, const f16* __restrict__ Vt,
    f16* __restrict__ attnB)
{
    __shared__ __align__(16) f16 Ks[64 * 64];
    __shared__ __align__(16) f16 Vs[64 * 64];          // [dk][kv]
    __shared__ __align__(16) f16 Ps[4 * 32 * 64];      // per-wave P re-layout

    const int tid = threadIdx.x, lane = tid & 63, wid = tid >> 6;
    const int lrow = lane & 15, lk = lane >> 4;
    const int bh = blockIdx.y;               // b*16+h
    const int b = bh >> 4, h = bh & 15;
    const int q0b = blockIdx.x * 128;
    const int q0w = q0b + wid * 32;          // this wave's 32 q-rows

    const f16* Qb = Q  + (size_t)bh * SS * DKK;
    const f16* Kb = K  + (size_t)bh * SS * DKK;
    const f16* Vb = Vt + (size_t)bh * DKK * SS;

    // Q fragments hoisted to registers: qf[mi][kk]
    f16x8 qf[2][2];
#pragma unroll
    for (int mi = 0; mi < 2; ++mi)
#pragma unroll
        for (int kk = 0; kk < 2; ++kk)
            qf[mi][kk] = *(const f16x8*)&Qb[(size_t)(q0w + mi * 16 + lrow) * DKK + kk * 32 + lk * 8];

    f32x4 oacc[2][4] = {};
    float mstate[2][4], lstate[2][4];
#pragma unroll
    for (int mi = 0; mi < 2; ++mi)
#pragma unroll
        for (int r = 0; r < 4; ++r) { mstate[mi][r] = -1e30f; lstate[mi][r] = 0.0f; }

    const int ntiles = (q0b + 128) / 64;     // causal: only tiles with kv0 <= q_max

    for (int t = 0; t < ntiles; ++t) {
        const int kv0 = t * 64;
        // stage K[kv][dk] and Vt[dk][kv] tiles (8KB each)
#pragma unroll
        for (int j = 0; j < 2; ++j) {
            int ci = (j * 4 + wid) * 64 + lane;
            int r = ci >> 3, c8 = (ci & 7) * 8;
            GLD16(Kb + (size_t)(kv0 + r) * DKK + c8, Ks + (j * 4 + wid) * 512);
            GLD16(Vb + (size_t)r * SS + kv0 + c8,    Vs + (j * 4 + wid) * 512);
        }
        __syncthreads();
        if (kv0 <= q0w + 31) {   // wave has at least one unmasked column
            // scores = Q K^T (Q pre-scaled by 1/8)
            f32x4 sacc[2][4] = {};
#pragma unroll
            for (int ni = 0; ni < 4; ++ni)
#pragma unroll
                for (int kk = 0; kk < 2; ++kk) {
                    f16x8 kf = *(const f16x8*)&Ks[(ni * 16 + lrow) * 64 + kk * 32 + lk * 8];
#pragma unroll
                    for (int mi = 0; mi < 2; ++mi)
                        sacc[mi][ni] = __builtin_amdgcn_mfma_f32_16x16x32_f16(
                            qf[mi][kk], kf, sacc[mi][ni], 0, 0, 0);
                }
            // online softmax per row (wave-parallel shfl reduce over 16 lanes)
#pragma unroll
            for (int mi = 0; mi < 2; ++mi)
#pragma unroll
                for (int r = 0; r < 4; ++r) {
                    int row = q0w + mi * 16 + lk * 4 + r;
                    float sv[4], smax = -1e30f;
#pragma unroll
                    for (int ni = 0; ni < 4; ++ni) {
                        float s = sacc[mi][ni][r];
                        int col = kv0 + ni * 16 + lrow;
                        if (col > row) s = -1e30f;   // causal mask
                        sv[ni] = s;
                        smax = fmaxf(smax, s);
                    }
#pragma unroll
                    for (int off = 1; off < 16; off <<= 1)
                        smax = fmaxf(smax, __shfl_xor(smax, off));
                    float mnew  = fmaxf(mstate[mi][r], smax);
                    float alpha = __expf(mstate[mi][r] - mnew);
                    mstate[mi][r] = mnew;
                    float rsum = 0.0f;
#pragma unroll
                    for (int ni = 0; ni < 4; ++ni) {
                        float p = __expf(sv[ni] - mnew);
                        rsum += p;
                        Ps[wid * 2048 + (mi * 16 + lk * 4 + r) * 64 + ni * 16 + lrow] = (f16)p;
                    }
#pragma unroll
                    for (int off = 1; off < 16; off <<= 1)
                        rsum += __shfl_xor(rsum, off);
                    lstate[mi][r] = lstate[mi][r] * alpha + rsum;
#pragma unroll
                    for (int no = 0; no < 4; ++no)
                        oacc[mi][no][r] *= alpha;
                }
            // PV: P[32x64] (via per-wave LDS re-layout) x V[64x64]
#pragma unroll
            for (int no = 0; no < 4; ++no)
#pragma unroll
                for (int kk = 0; kk < 2; ++kk) {
                    f16x8 vf = *(const f16x8*)&Vs[(no * 16 + lrow) * 64 + kk * 32 + lk * 8];
#pragma unroll
                    for (int mi = 0; mi < 2; ++mi) {
                        f16x8 pa = *(const f16x8*)&Ps[wid * 2048 + (mi * 16 + lrow) * 64 + kk * 32 + lk * 8];
                        oacc[mi][no] = __builtin_amdgcn_mfma_f32_16x16x32_f16(
                            pa, vf, oacc[mi][no], 0, 0, 0);
                    }
                }
        }
        __syncthreads();   // before next stage overwrites Ks/Vs
    }

    // normalize + store attn[b,s,h,dk] (f16) for out-proj GEMM
#pragma unroll
    for (int mi = 0; mi < 2; ++mi)
#pragma unroll
        for (int no = 0; no < 4; ++no)
#pragma unroll
            for (int r = 0; r < 4; ++r) {
                int row = q0w + mi * 16 + lk * 4 + r;
                int col = no * 16 + lrow;
                float v = oacc[mi][no][r] / lstate[mi][r];
                attnB[((size_t)(b * SS) + row) * DD + h * DKK + col] = (f16)v;
            }
}

// ---------------- Out projection GEMM (f32 output) ----------------
__global__ __launch_bounds__(256) void out_gemm(
    const f16* __restrict__ attnB, const f16* __restrict__ wob, float* __restrict__ out)
{
    __shared__ __align__(16) f16 As[128 * 32];
    __shared__ __align__(16) f16 Bs[128 * 32];
    const int bm = blockIdx.y * 128, bn = blockIdx.x * 128;
    f32x4 acc[4][4] = {};
    gemm_core(attnB, wob, As, Bs, acc, bm, bn);
    const int tid = threadIdx.x, lane = tid & 63, wid = tid >> 6;
    const int lrow = lane & 15, lk = lane >> 4;
    const int wm = (wid >> 1) * 64, wn = (wid & 1) * 64;
#pragma unroll
    for (int mi = 0; mi < 4; ++mi)
#pragma unroll
        for (int ni = 0; ni < 4; ++ni)
#pragma unroll
            for (int r = 0; r < 4; ++r) {
                int row = bm + wm + mi * 16 + lk * 4 + r;
                int col = bn + wn + ni * 16 + lrow;
                out[(size_t)row * 1024 + col] = acc[mi][ni][r];
            }
}

// ---------------------------------------------------------------------------
extern "C" void kernel_launch(void* const* d_in, const int* in_sizes, int n_in,
                              void* d_out, int out_size, void* d_ws, size_t ws_size,
                              hipStream_t stream) {
    const float* x  = (const float*)d_in[0];
    const float* wq = (const float*)d_in[1];
    const float* wk = (const float*)d_in[2];
    const float* wv = (const float*)d_in[3];
    const float* wo = (const float*)d_in[4];
    float* out = (float*)d_out;

    // workspace layout (f16 elements); attnB aliases xb (xb dead after QKV gemm)
    constexpr size_t NXB = (size_t)MM * DD;   // 8388608
    constexpr size_t NW  = (size_t)DD * DD;   // 1048576
    f16* xb  = (f16*)d_ws;
    f16* wqb = xb  + NXB;
    f16* wkb = wqb + NW;
    f16* wvb = wkb + NW;
    f16* wob = wvb + NW;
    f16* Qr  = wob + NW;
    f16* Kr  = Qr  + NXB;
    f16* Vt  = Kr  + NXB;
    float* ctab = (float*)(Vt + NXB);
    float* stab = ctab + SS * DKK;
    f16* attnB = xb;

    cvt_kernel<<<2048, 256, 0, stream>>>((const float4*)x,  (f16x4*)xb,  (int)(NXB / 4));
    cvt_kernel<<<512,  256, 0, stream>>>((const float4*)wq, (f16x4*)wqb, (int)(NW / 4));
    cvt_kernel<<<512,  256, 0, stream>>>((const float4*)wk, (f16x4*)wkb, (int)(NW / 4));
    cvt_kernel<<<512,  256, 0, stream>>>((const float4*)wv, (f16x4*)wvb, (int)(NW / 4));
    cvt_kernel<<<512,  256, 0, stream>>>((const float4*)wo, (f16x4*)wob, (int)(NW / 4));
    rope_tab_kernel<<<(SS * DKK + 255) / 256, 256, 0, stream>>>(ctab, stab);

    qkv_gemm<<<dim3(8, 64, 3), 256, 0, stream>>>(xb, wqb, wkb, wvb, Qr, Kr, Vt, ctab, stab);
    attn_kernel<<<dim3(16, 64), 256, 0, stream>>>(Qr, Kr, Vt, attnB);
    out_gemm<<<dim3(8, 64), 256, 0, stream>>>(attnB, wob, out);
}

// Round 2
// 289.533 us; speedup vs baseline: 1.4264x; 1.4264x over previous
//
#include <hip/hip_runtime.h>

// ---------------------------------------------------------------------------
// MultiHeadSelfAttention: B=4 S=2048 D=1024 H=16 DK=64, RoPE, causal, out-proj
// Round 2: causal-paired balanced attention grid, K/V prefetch double-buffer,
//          XOR bank-conflict swizzles (attn + GEMM), GEMM BK=64.
// ---------------------------------------------------------------------------

typedef _Float16 f16;
typedef _Float16 f16x4 __attribute__((ext_vector_type(4)));
typedef _Float16 f16x8 __attribute__((ext_vector_type(8)));
typedef float    f32x4 __attribute__((ext_vector_type(4)));

typedef __attribute__((address_space(1))) void gvoid_t;
typedef __attribute__((address_space(3))) void lvoid_t;

// async global->LDS, 16B per lane; LDS dest = wave-uniform base + lane*16
#define GLD16(g, l) __builtin_amdgcn_global_load_lds( \
    (gvoid_t*)(const void*)(g), (lvoid_t*)(l), 16, 0, 0)

constexpr int BB = 4, SS = 2048, DD = 1024, HH = 16, DKK = 64;
constexpr int MM = BB * SS;  // 8192

// ---------------- f32 -> f16 convert (vectorized) ----------------
__global__ void cvt_kernel(const float4* __restrict__ in, f16x4* __restrict__ out, int n4) {
    int stride = gridDim.x * blockDim.x;
    for (int i = blockIdx.x * blockDim.x + threadIdx.x; i < n4; i += stride) {
        float4 v = in[i];
        f16x4 o;
        o[0] = (f16)v.x; o[1] = (f16)v.y; o[2] = (f16)v.z; o[3] = (f16)v.w;
        out[i] = o;
    }
}

// ---------------- RoPE tables: ctab/stab[s][dk] = cos/sin(s * invfreq[dk>>1])
__global__ void rope_tab_kernel(float* __restrict__ ctab, float* __restrict__ stab) {
    int idx = blockIdx.x * blockDim.x + threadIdx.x;
    if (idx >= SS * DKK) return;
    int s = idx >> 6, dk = idx & 63, i = dk >> 1;
    float inv = powf(10000.0f, -(float)(2 * i) / (float)DKK);
    float ang = (float)s * inv;
    ctab[idx] = cosf(ang);
    stab[idx] = sinf(ang);
}

// ---------------- GEMM core: C[128x128] tile, A[M][K], B-as-[N][K], K=1024 ---
// BK=64 (128B rows -> full 8-slot XOR swizzle), global_load_lds staging,
// 16x16x32 f16 MFMA, 4 waves 2x2.
__device__ __forceinline__ void gemm_core(
    const f16* __restrict__ A, const f16* __restrict__ Bm,
    f16* As, f16* Bs, f32x4 (&acc)[4][4], int bm, int bn)
{
    const int tid  = threadIdx.x;
    const int lane = tid & 63, wid = tid >> 6;
    const int lrow = lane & 15, lk = lane >> 4;
    const int wm = (wid >> 1) * 64, wn = (wid & 1) * 64;

    for (int k0 = 0; k0 < 1024; k0 += 64) {
        // stage 128x64 f16 tiles: 1024 chunks of 16B each, pre-swizzled source
#pragma unroll
        for (int j = 0; j < 4; ++j) {
            int ci = j * 256 + tid;
            int r = ci >> 3, c = ci & 7;
            int cs = (c ^ (r & 7)) * 8;
            GLD16(A  + (size_t)(bm + r) * 1024 + k0 + cs, As + (j * 256 + wid * 64) * 8);
            GLD16(Bm + (size_t)(bn + r) * 1024 + k0 + cs, Bs + (j * 256 + wid * 64) * 8);
        }
        __syncthreads();
#pragma unroll
        for (int kk = 0; kk < 2; ++kk) {
            f16x8 af[4], bf[4];
#pragma unroll
            for (int mi = 0; mi < 4; ++mi) {
                int row = wm + mi * 16 + lrow;
                af[mi] = *(const f16x8*)&As[row * 64 + ((kk * 4 + lk) ^ (row & 7)) * 8];
            }
#pragma unroll
            for (int ni = 0; ni < 4; ++ni) {
                int row = wn + ni * 16 + lrow;
                bf[ni] = *(const f16x8*)&Bs[row * 64 + ((kk * 4 + lk) ^ (row & 7)) * 8];
            }
#pragma unroll
            for (int mi = 0; mi < 4; ++mi)
#pragma unroll
                for (int ni = 0; ni < 4; ++ni)
                    acc[mi][ni] = __builtin_amdgcn_mfma_f32_16x16x32_f16(
                        af[mi], bf[ni], acc[mi][ni], 0, 0, 0);
        }
        __syncthreads();
    }
}

// ---------------- QKV GEMM + RoPE epilogue; z: 0=Q 1=K 2=V ----------------
__global__ __launch_bounds__(256) void qkv_gemm(
    const f16* __restrict__ xb,
    const f16* __restrict__ wqb, const f16* __restrict__ wkb, const f16* __restrict__ wvb,
    f16* __restrict__ Qr, f16* __restrict__ Kr, f16* __restrict__ Vt,
    const float* __restrict__ ctab, const float* __restrict__ stab)
{
    __shared__ __align__(16) f16 As[128 * 64];
    __shared__ __align__(16) f16 Bs[128 * 64];
    const int z = blockIdx.z;
    const f16* Bm = (z == 0) ? wqb : (z == 1) ? wkb : wvb;
    const int bm = blockIdx.y * 128, bn = blockIdx.x * 128;
    f32x4 acc[4][4] = {};
    gemm_core(xb, Bm, As, Bs, acc, bm, bn);

    const int tid = threadIdx.x, lane = tid & 63, wid = tid >> 6;
    const int lrow = lane & 15, lk = lane >> 4;
    const int wm = (wid >> 1) * 64, wn = (wid & 1) * 64;

    if (z == 2) {
        // V stored transposed: [b,h,dk,s] so attention stages Vt rows directly
#pragma unroll
        for (int mi = 0; mi < 4; ++mi)
#pragma unroll
            for (int ni = 0; ni < 4; ++ni)
#pragma unroll
                for (int r = 0; r < 4; ++r) {
                    int row = bm + wm + mi * 16 + lk * 4 + r;   // (b,s)
                    int col = bn + wn + ni * 16 + lrow;          // (h,dk)
                    int b = row >> 11, s = row & 2047, h = col >> 6, dk = col & 63;
                    Vt[((size_t)(b * HH + h) * DKK + dk) * SS + s] = (f16)acc[mi][ni][r];
                }
    } else {
        f16* Out = (z == 0) ? Qr : Kr;
        const float scale = (z == 0) ? 0.125f : 1.0f;  // fold 1/sqrt(DK) into Q
#pragma unroll
        for (int mi = 0; mi < 4; ++mi)
#pragma unroll
            for (int ni = 0; ni < 4; ++ni)
#pragma unroll
                for (int r = 0; r < 4; ++r) {
                    int row = bm + wm + mi * 16 + lk * 4 + r;
                    int col = bn + wn + ni * 16 + lrow;
                    int b = row >> 11, s = row & 2047, h = col >> 6, dk = col & 63;
                    float v = acc[mi][ni][r];
                    float partner = __shfl_xor(v, 1);   // adjacent column (same rows)
                    float cc = ctab[s * DKK + dk], ssn = stab[s * DKK + dk];
                    float rot = (col & 1) ? partner : -partner;
                    float o = (v * cc + rot * ssn) * scale;
                    Out[((size_t)(b * HH + h) * SS + s) * DKK + dk] = (f16)o;
                }
    }
}

// ---------------- Flash attention ----------------
// q-tiles of 64 rows; block px handles q-tiles {px, 31-px} => 33 KV-tiles each
// (perfect causal balance). 4 waves x 16 q-rows. K/V double-buffered with
// prefetch; XOR swizzle on Ks/Vs/Ps (pre-swizzled global source, linear LDS
// dest, swizzled reads).
__global__ __launch_bounds__(256, 4) void attn_kernel(
    const f16* __restrict__ Q, const f16* __restrict__ K, const f16* __restrict__ Vt,
    f16* __restrict__ attnB)
{
    __shared__ __align__(16) f16 Ks[2][64 * 64];   // [kv][dk], swizzled
    __shared__ __align__(16) f16 Vs[2][64 * 64];   // [dk][kv], swizzled
    __shared__ __align__(16) f16 Ps[4][16 * 64];   // per-wave P[q][kv], swizzled

    const int tid = threadIdx.x, lane = tid & 63, wid = tid >> 6;
    const int lrow = lane & 15, lk = lane >> 4;
    const int bh = blockIdx.y;               // b*16+h
    const int b = bh >> 4, h = bh & 15;
    const int px = blockIdx.x;               // 0..15

    const f16* Qb = Q  + (size_t)bh * SS * DKK;
    const f16* Kb = K  + (size_t)bh * SS * DKK;
    const f16* Vb = Vt + (size_t)bh * DKK * SS;
    f16* PsW = &Ps[wid][0];

    int cur = 0;

    for (int pass = 0; pass < 2; ++pass) {
        const int qt  = pass ? (31 - px) : px;   // q-tile index (64 rows)
        const int q0b = qt * 64;
        const int q0w = q0b + wid * 16;          // this wave's 16 q-rows
        const int nt  = qt + 1;                  // causal KV tiles

        // Q fragments in registers
        f16x8 qf[2];
#pragma unroll
        for (int kk = 0; kk < 2; ++kk)
            qf[kk] = *(const f16x8*)&Qb[(size_t)(q0w + lrow) * DKK + kk * 32 + lk * 8];

        f32x4 oacc[4] = {};
        float mstate[4], lstate[4];
#pragma unroll
        for (int r = 0; r < 4; ++r) { mstate[r] = -1e30f; lstate[r] = 0.0f; }

        // prologue stage tile 0
#pragma unroll
        for (int j = 0; j < 2; ++j) {
            int ci = j * 256 + tid;
            int r = ci >> 3, c = ci & 7;
            int cs = (c ^ (r & 7)) * 8;
            GLD16(Kb + (size_t)r * DKK + cs,  &Ks[cur][(j * 256 + wid * 64) * 8]);
            GLD16(Vb + (size_t)r * SS  + cs,  &Vs[cur][(j * 256 + wid * 64) * 8]);
        }
        __syncthreads();

        for (int t = 0; t < nt; ++t) {
            const int kv0 = t * 64;
            // prefetch next KV tile into other buffer
            if (t + 1 < nt) {
                const int kvn = kv0 + 64;
#pragma unroll
                for (int j = 0; j < 2; ++j) {
                    int ci = j * 256 + tid;
                    int r = ci >> 3, c = ci & 7;
                    int cs = (c ^ (r & 7)) * 8;
                    GLD16(Kb + (size_t)(kvn + r) * DKK + cs, &Ks[cur ^ 1][(j * 256 + wid * 64) * 8]);
                    GLD16(Vb + (size_t)r * SS + kvn + cs,    &Vs[cur ^ 1][(j * 256 + wid * 64) * 8]);
                }
            }

            // ---- QK^T: S[16 q][64 kv] per wave (Q pre-scaled by 1/8) ----
            f32x4 sacc[4] = {};
#pragma unroll
            for (int kk = 0; kk < 2; ++kk)
#pragma unroll
                for (int ni = 0; ni < 4; ++ni) {
                    int row = ni * 16 + lrow;
                    f16x8 kf = *(const f16x8*)&Ks[cur][row * 64 + ((kk * 4 + lk) ^ (row & 7)) * 8];
                    sacc[ni] = __builtin_amdgcn_mfma_f32_16x16x32_f16(qf[kk], kf, sacc[ni], 0, 0, 0);
                }

            // ---- online softmax (4 rows/lane-group; reduce over 16 lanes) ----
            const bool diag = (t == nt - 1);
#pragma unroll
            for (int r = 0; r < 4; ++r) {
                const int q = lk * 4 + r;            // local q row 0..15
                const int qrow = q0w + q;            // global
                float sv[4], smax = -1e30f;
#pragma unroll
                for (int ni = 0; ni < 4; ++ni) {
                    float s = sacc[ni][r];
                    if (diag && (kv0 + ni * 16 + lrow > qrow)) s = -1e30f;
                    sv[ni] = s;
                    smax = fmaxf(smax, s);
                }
#pragma unroll
                for (int off = 1; off < 16; off <<= 1)
                    smax = fmaxf(smax, __shfl_xor(smax, off));
                float mnew  = fmaxf(mstate[r], smax);
                float alpha = __expf(mstate[r] - mnew);
                mstate[r] = mnew;
                float rsum = 0.0f;
#pragma unroll
                for (int ni = 0; ni < 4; ++ni) {
                    float p = __expf(sv[ni] - mnew);
                    rsum += p;
                    // P[q][kv] with chunk ^= q&7
                    PsW[q * 64 + (((ni * 2 + (lrow >> 3)) ^ (q & 7)) * 8) + (lrow & 7)] = (f16)p;
                }
#pragma unroll
                for (int off = 1; off < 16; off <<= 1)
                    rsum += __shfl_xor(rsum, off);
                lstate[r] = lstate[r] * alpha + rsum;
#pragma unroll
                for (int no = 0; no < 4; ++no)
                    oacc[no][r] *= alpha;
            }

            // ---- PV: O[16 q][64 dk] += P[16 q][64 kv] x V[64 kv][64 dk] ----
            f16x8 pa[2];
#pragma unroll
            for (int kk = 0; kk < 2; ++kk)
                pa[kk] = *(const f16x8*)&PsW[lrow * 64 + ((kk * 4 + lk) ^ (lrow & 7)) * 8];
#pragma unroll
            for (int no = 0; no < 4; ++no)
#pragma unroll
                for (int kk = 0; kk < 2; ++kk) {
                    int row = no * 16 + lrow;
                    f16x8 vf = *(const f16x8*)&Vs[cur][row * 64 + ((kk * 4 + lk) ^ (row & 7)) * 8];
                    oacc[no] = __builtin_amdgcn_mfma_f32_16x16x32_f16(pa[kk], vf, oacc[no], 0, 0, 0);
                }

            __syncthreads();   // prefetch complete + everyone done reading cur
            cur ^= 1;
        }

        // normalize + store attn[b,s,h,dk] (f16) for out-proj GEMM
#pragma unroll
        for (int no = 0; no < 4; ++no)
#pragma unroll
            for (int r = 0; r < 4; ++r) {
                int row = q0w + lk * 4 + r;
                int col = no * 16 + lrow;
                float v = oacc[no][r] / lstate[r];
                attnB[((size_t)(b * SS) + row) * DD + h * DKK + col] = (f16)v;
            }
    }
}

// ---------------- Out projection GEMM (f32 output) ----------------
__global__ __launch_bounds__(256) void out_gemm(
    const f16* __restrict__ attnB, const f16* __restrict__ wob, float* __restrict__ out)
{
    __shared__ __align__(16) f16 As[128 * 64];
    __shared__ __align__(16) f16 Bs[128 * 64];
    const int bm = blockIdx.y * 128, bn = blockIdx.x * 128;
    f32x4 acc[4][4] = {};
    gemm_core(attnB, wob, As, Bs, acc, bm, bn);
    const int tid = threadIdx.x, lane = tid & 63, wid = tid >> 6;
    const int lrow = lane & 15, lk = lane >> 4;
    const int wm = (wid >> 1) * 64, wn = (wid & 1) * 64;
#pragma unroll
    for (int mi = 0; mi < 4; ++mi)
#pragma unroll
        for (int ni = 0; ni < 4; ++ni)
#pragma unroll
            for (int r = 0; r < 4; ++r) {
                int row = bm + wm + mi * 16 + lk * 4 + r;
                int col = bn + wn + ni * 16 + lrow;
                out[(size_t)row * 1024 + col] = acc[mi][ni][r];
            }
}

// ---------------------------------------------------------------------------
extern "C" void kernel_launch(void* const* d_in, const int* in_sizes, int n_in,
                              void* d_out, int out_size, void* d_ws, size_t ws_size,
                              hipStream_t stream) {
    const float* x  = (const float*)d_in[0];
    const float* wq = (const float*)d_in[1];
    const float* wk = (const float*)d_in[2];
    const float* wv = (const float*)d_in[3];
    const float* wo = (const float*)d_in[4];
    float* out = (float*)d_out;

    // workspace layout (f16 elements); attnB aliases xb (xb dead after QKV gemm)
    constexpr size_t NXB = (size_t)MM * DD;   // 8388608
    constexpr size_t NW  = (size_t)DD * DD;   // 1048576
    f16* xb  = (f16*)d_ws;
    f16* wqb = xb  + NXB;
    f16* wkb = wqb + NW;
    f16* wvb = wkb + NW;
    f16* wob = wvb + NW;
    f16* Qr  = wob + NW;
    f16* Kr  = Qr  + NXB;
    f16* Vt  = Kr  + NXB;
    float* ctab = (float*)(Vt + NXB);
    float* stab = ctab + SS * DKK;
    f16* attnB = xb;

    cvt_kernel<<<2048, 256, 0, stream>>>((const float4*)x,  (f16x4*)xb,  (int)(NXB / 4));
    cvt_kernel<<<512,  256, 0, stream>>>((const float4*)wq, (f16x4*)wqb, (int)(NW / 4));
    cvt_kernel<<<512,  256, 0, stream>>>((const float4*)wk, (f16x4*)wkb, (int)(NW / 4));
    cvt_kernel<<<512,  256, 0, stream>>>((const float4*)wv, (f16x4*)wvb, (int)(NW / 4));
    cvt_kernel<<<512,  256, 0, stream>>>((const float4*)wo, (f16x4*)wob, (int)(NW / 4));
    rope_tab_kernel<<<(SS * DKK + 255) / 256, 256, 0, stream>>>(ctab, stab);

    qkv_gemm<<<dim3(8, 64, 3), 256, 0, stream>>>(xb, wqb, wkb, wvb, Qr, Kr, Vt, ctab, stab);
    attn_kernel<<<dim3(16, 64), 256, 0, stream>>>(Qr, Kr, Vt, attnB);
    out_gemm<<<dim3(8, 64), 256, 0, stream>>>(attnB, wob, out);
}

// Round 3
// 232.528 us; speedup vs baseline: 1.7760x; 1.2452x over previous
//
#include <hip/hip_runtime.h>

// ---------------------------------------------------------------------------
// MultiHeadSelfAttention: B=4 S=2048 D=1024 H=16 DK=64, RoPE, causal, out-proj
// Round 3: GEMM K-loop -> 2-phase double-buffer (stage t+1 before compute t,
//          ONE barrier per K-step).  Attn unchanged (conflicts already 0).
// ---------------------------------------------------------------------------

typedef _Float16 f16;
typedef _Float16 f16x4 __attribute__((ext_vector_type(4)));
typedef _Float16 f16x8 __attribute__((ext_vector_type(8)));
typedef float    f32x4 __attribute__((ext_vector_type(4)));

typedef __attribute__((address_space(1))) void gvoid_t;
typedef __attribute__((address_space(3))) void lvoid_t;

// async global->LDS, 16B per lane; LDS dest = wave-uniform base + lane*16
#define GLD16(g, l) __builtin_amdgcn_global_load_lds( \
    (gvoid_t*)(const void*)(g), (lvoid_t*)(l), 16, 0, 0)

constexpr int BB = 4, SS = 2048, DD = 1024, HH = 16, DKK = 64;
constexpr int MM = BB * SS;  // 8192

// ---------------- f32 -> f16 convert (vectorized) ----------------
__global__ void cvt_kernel(const float4* __restrict__ in, f16x4* __restrict__ out, int n4) {
    int stride = gridDim.x * blockDim.x;
    for (int i = blockIdx.x * blockDim.x + threadIdx.x; i < n4; i += stride) {
        float4 v = in[i];
        f16x4 o;
        o[0] = (f16)v.x; o[1] = (f16)v.y; o[2] = (f16)v.z; o[3] = (f16)v.w;
        out[i] = o;
    }
}

// 4 weight matrices in one launch; dst regions are contiguous in ws
__global__ void cvt4_kernel(const float4* __restrict__ a, const float4* __restrict__ b,
                            const float4* __restrict__ c, const float4* __restrict__ d,
                            f16x4* __restrict__ out, int n4per) {
    const float4* srcs[4] = {a, b, c, d};
    const float4* src = srcs[blockIdx.y];
    f16x4* dst = out + (size_t)blockIdx.y * n4per;
    int stride = gridDim.x * blockDim.x;
    for (int i = blockIdx.x * blockDim.x + threadIdx.x; i < n4per; i += stride) {
        float4 v = src[i];
        f16x4 o;
        o[0] = (f16)v.x; o[1] = (f16)v.y; o[2] = (f16)v.z; o[3] = (f16)v.w;
        dst[i] = o;
    }
}

// ---------------- RoPE tables: ctab/stab[s][dk] = cos/sin(s * invfreq[dk>>1])
__global__ void rope_tab_kernel(float* __restrict__ ctab, float* __restrict__ stab) {
    int idx = blockIdx.x * blockDim.x + threadIdx.x;
    if (idx >= SS * DKK) return;
    int s = idx >> 6, dk = idx & 63, i = dk >> 1;
    float inv = powf(10000.0f, -(float)(2 * i) / (float)DKK);
    float ang = (float)s * inv;
    ctab[idx] = cosf(ang);
    stab[idx] = sinf(ang);
}

// ---------------- GEMM core: C[128x128] tile, A[M][K], B-as-[N][K], K=1024 ---
// BK=64, double-buffered LDS (2x16KB per matrix), global_load_lds staging with
// XOR-swizzled source, ONE barrier per K-step, 16x16x32 f16 MFMA, 4 waves 2x2.
__device__ __forceinline__ void gemm_core(
    const f16* __restrict__ A, const f16* __restrict__ Bm,
    f16* As, f16* Bs, f32x4 (&acc)[4][4], int bm, int bn)
{
    const int tid  = threadIdx.x;
    const int lane = tid & 63, wid = tid >> 6;
    const int lrow = lane & 15, lk = lane >> 4;
    const int wm = (wid >> 1) * 64, wn = (wid & 1) * 64;

    // staging addressing (constant across K-steps)
    const int r_ = tid >> 3, c_ = tid & 7;
    const int cs_ = (c_ ^ (r_ & 7)) * 8;

    auto STAGE = [&](int buf, int k0) {
#pragma unroll
        for (int j = 0; j < 4; ++j) {
            int r = j * 32 + r_;
            int cs = (c_ ^ (r & 7)) * 8;          // r&7 == r_&7, but keep exact
            GLD16(A  + (size_t)(bm + r) * 1024 + k0 + cs, As + buf * 8192 + (j * 256 + wid * 64) * 8);
            GLD16(Bm + (size_t)(bn + r) * 1024 + k0 + cs, Bs + buf * 8192 + (j * 256 + wid * 64) * 8);
        }
    };

    auto COMPUTE = [&](int buf) {
        const f16* Ab = As + buf * 8192;
        const f16* Bb = Bs + buf * 8192;
#pragma unroll
        for (int kk = 0; kk < 2; ++kk) {
            f16x8 af[4], bf[4];
#pragma unroll
            for (int mi = 0; mi < 4; ++mi) {
                int row = wm + mi * 16 + lrow;
                af[mi] = *(const f16x8*)&Ab[row * 64 + ((kk * 4 + lk) ^ (row & 7)) * 8];
            }
#pragma unroll
            for (int ni = 0; ni < 4; ++ni) {
                int row = wn + ni * 16 + lrow;
                bf[ni] = *(const f16x8*)&Bb[row * 64 + ((kk * 4 + lk) ^ (row & 7)) * 8];
            }
#pragma unroll
            for (int mi = 0; mi < 4; ++mi)
#pragma unroll
                for (int ni = 0; ni < 4; ++ni)
                    acc[mi][ni] = __builtin_amdgcn_mfma_f32_16x16x32_f16(
                        af[mi], bf[ni], acc[mi][ni], 0, 0, 0);
        }
    };

    STAGE(0, 0);
    __syncthreads();
    int cur = 0;
#pragma unroll 1
    for (int t = 0; t < 15; ++t) {
        STAGE(cur ^ 1, (t + 1) * 64);   // issue next tile FIRST (hides under MFMA)
        COMPUTE(cur);
        __syncthreads();                // drains vmcnt(0): next buffer ready
        cur ^= 1;
    }
    COMPUTE(cur);                       // tail, no prefetch
    (void)cs_;
}

// ---------------- QKV GEMM + RoPE epilogue; z: 0=Q 1=K 2=V ----------------
__global__ __launch_bounds__(256) void qkv_gemm(
    const f16* __restrict__ xb,
    const f16* __restrict__ wqb, const f16* __restrict__ wkb, const f16* __restrict__ wvb,
    f16* __restrict__ Qr, f16* __restrict__ Kr, f16* __restrict__ Vt,
    const float* __restrict__ ctab, const float* __restrict__ stab)
{
    __shared__ __align__(16) f16 As[2 * 128 * 64];
    __shared__ __align__(16) f16 Bs[2 * 128 * 64];
    const int z = blockIdx.z;
    const f16* Bm = (z == 0) ? wqb : (z == 1) ? wkb : wvb;
    const int bm = blockIdx.y * 128, bn = blockIdx.x * 128;
    f32x4 acc[4][4] = {};
    gemm_core(xb, Bm, As, Bs, acc, bm, bn);

    const int tid = threadIdx.x, lane = tid & 63, wid = tid >> 6;
    const int lrow = lane & 15, lk = lane >> 4;
    const int wm = (wid >> 1) * 64, wn = (wid & 1) * 64;

    if (z == 2) {
        // V stored transposed: [b,h,dk,s] so attention stages Vt rows directly
#pragma unroll
        for (int mi = 0; mi < 4; ++mi)
#pragma unroll
            for (int ni = 0; ni < 4; ++ni)
#pragma unroll
                for (int r = 0; r < 4; ++r) {
                    int row = bm + wm + mi * 16 + lk * 4 + r;   // (b,s)
                    int col = bn + wn + ni * 16 + lrow;          // (h,dk)
                    int b = row >> 11, s = row & 2047, h = col >> 6, dk = col & 63;
                    Vt[((size_t)(b * HH + h) * DKK + dk) * SS + s] = (f16)acc[mi][ni][r];
                }
    } else {
        f16* Out = (z == 0) ? Qr : Kr;
        const float scale = (z == 0) ? 0.125f : 1.0f;  // fold 1/sqrt(DK) into Q
#pragma unroll
        for (int mi = 0; mi < 4; ++mi)
#pragma unroll
            for (int ni = 0; ni < 4; ++ni)
#pragma unroll
                for (int r = 0; r < 4; ++r) {
                    int row = bm + wm + mi * 16 + lk * 4 + r;
                    int col = bn + wn + ni * 16 + lrow;
                    int b = row >> 11, s = row & 2047, h = col >> 6, dk = col & 63;
                    float v = acc[mi][ni][r];
                    float partner = __shfl_xor(v, 1);   // adjacent column (same rows)
                    float cc = ctab[s * DKK + dk], ssn = stab[s * DKK + dk];
                    float rot = (col & 1) ? partner : -partner;
                    float o = (v * cc + rot * ssn) * scale;
                    Out[((size_t)(b * HH + h) * SS + s) * DKK + dk] = (f16)o;
                }
    }
}

// ---------------- Flash attention ----------------
// q-tiles of 64 rows; block px handles q-tiles {px, 31-px} => 33 KV-tiles each
// (perfect causal balance). 4 waves x 16 q-rows. K/V double-buffered with
// prefetch; XOR swizzle on Ks/Vs/Ps.
__global__ __launch_bounds__(256, 4) void attn_kernel(
    const f16* __restrict__ Q, const f16* __restrict__ K, const f16* __restrict__ Vt,
    f16* __restrict__ attnB)
{
    __shared__ __align__(16) f16 Ks[2][64 * 64];   // [kv][dk], swizzled
    __shared__ __align__(16) f16 Vs[2][64 * 64];   // [dk][kv], swizzled
    __shared__ __align__(16) f16 Ps[4][16 * 64];   // per-wave P[q][kv], swizzled

    const int tid = threadIdx.x, lane = tid & 63, wid = tid >> 6;
    const int lrow = lane & 15, lk = lane >> 4;
    const int bh = blockIdx.y;               // b*16+h
    const int b = bh >> 4, h = bh & 15;
    const int px = blockIdx.x;               // 0..15

    const f16* Qb = Q  + (size_t)bh * SS * DKK;
    const f16* Kb = K  + (size_t)bh * SS * DKK;
    const f16* Vb = Vt + (size_t)bh * DKK * SS;
    f16* PsW = &Ps[wid][0];

    int cur = 0;

    for (int pass = 0; pass < 2; ++pass) {
        const int qt  = pass ? (31 - px) : px;   // q-tile index (64 rows)
        const int q0b = qt * 64;
        const int q0w = q0b + wid * 16;          // this wave's 16 q-rows
        const int nt  = qt + 1;                  // causal KV tiles

        // Q fragments in registers
        f16x8 qf[2];
#pragma unroll
        for (int kk = 0; kk < 2; ++kk)
            qf[kk] = *(const f16x8*)&Qb[(size_t)(q0w + lrow) * DKK + kk * 32 + lk * 8];

        f32x4 oacc[4] = {};
        float mstate[4], lstate[4];
#pragma unroll
        for (int r = 0; r < 4; ++r) { mstate[r] = -1e30f; lstate[r] = 0.0f; }

        // prologue stage tile 0
#pragma unroll
        for (int j = 0; j < 2; ++j) {
            int ci = j * 256 + tid;
            int r = ci >> 3, c = ci & 7;
            int cs = (c ^ (r & 7)) * 8;
            GLD16(Kb + (size_t)r * DKK + cs,  &Ks[cur][(j * 256 + wid * 64) * 8]);
            GLD16(Vb + (size_t)r * SS  + cs,  &Vs[cur][(j * 256 + wid * 64) * 8]);
        }
        __syncthreads();

        for (int t = 0; t < nt; ++t) {
            const int kv0 = t * 64;
            // prefetch next KV tile into other buffer
            if (t + 1 < nt) {
                const int kvn = kv0 + 64;
#pragma unroll
                for (int j = 0; j < 2; ++j) {
                    int ci = j * 256 + tid;
                    int r = ci >> 3, c = ci & 7;
                    int cs = (c ^ (r & 7)) * 8;
                    GLD16(Kb + (size_t)(kvn + r) * DKK + cs, &Ks[cur ^ 1][(j * 256 + wid * 64) * 8]);
                    GLD16(Vb + (size_t)r * SS + kvn + cs,    &Vs[cur ^ 1][(j * 256 + wid * 64) * 8]);
                }
            }

            // ---- QK^T: S[16 q][64 kv] per wave (Q pre-scaled by 1/8) ----
            f32x4 sacc[4] = {};
#pragma unroll
            for (int kk = 0; kk < 2; ++kk)
#pragma unroll
                for (int ni = 0; ni < 4; ++ni) {
                    int row = ni * 16 + lrow;
                    f16x8 kf = *(const f16x8*)&Ks[cur][row * 64 + ((kk * 4 + lk) ^ (row & 7)) * 8];
                    sacc[ni] = __builtin_amdgcn_mfma_f32_16x16x32_f16(qf[kk], kf, sacc[ni], 0, 0, 0);
                }

            // ---- online softmax (4 rows/lane-group; reduce over 16 lanes) ----
            const bool diag = (t == nt - 1);
#pragma unroll
            for (int r = 0; r < 4; ++r) {
                const int q = lk * 4 + r;            // local q row 0..15
                const int qrow = q0w + q;            // global
                float sv[4], smax = -1e30f;
#pragma unroll
                for (int ni = 0; ni < 4; ++ni) {
                    float s = sacc[ni][r];
                    if (diag && (kv0 + ni * 16 + lrow > qrow)) s = -1e30f;
                    sv[ni] = s;
                    smax = fmaxf(smax, s);
                }
#pragma unroll
                for (int off = 1; off < 16; off <<= 1)
                    smax = fmaxf(smax, __shfl_xor(smax, off));
                float mnew  = fmaxf(mstate[r], smax);
                float alpha = __expf(mstate[r] - mnew);
                mstate[r] = mnew;
                float rsum = 0.0f;
#pragma unroll
                for (int ni = 0; ni < 4; ++ni) {
                    float p = __expf(sv[ni] - mnew);
                    rsum += p;
                    // P[q][kv] with chunk ^= q&7
                    PsW[q * 64 + (((ni * 2 + (lrow >> 3)) ^ (q & 7)) * 8) + (lrow & 7)] = (f16)p;
                }
#pragma unroll
                for (int off = 1; off < 16; off <<= 1)
                    rsum += __shfl_xor(rsum, off);
                lstate[r] = lstate[r] * alpha + rsum;
#pragma unroll
                for (int no = 0; no < 4; ++no)
                    oacc[no][r] *= alpha;
            }

            // ---- PV: O[16 q][64 dk] += P[16 q][64 kv] x V[64 kv][64 dk] ----
            f16x8 pa[2];
#pragma unroll
            for (int kk = 0; kk < 2; ++kk)
                pa[kk] = *(const f16x8*)&PsW[lrow * 64 + ((kk * 4 + lk) ^ (lrow & 7)) * 8];
#pragma unroll
            for (int no = 0; no < 4; ++no)
#pragma unroll
                for (int kk = 0; kk < 2; ++kk) {
                    int row = no * 16 + lrow;
                    f16x8 vf = *(const f16x8*)&Vs[cur][row * 64 + ((kk * 4 + lk) ^ (row & 7)) * 8];
                    oacc[no] = __builtin_amdgcn_mfma_f32_16x16x32_f16(pa[kk], vf, oacc[no], 0, 0, 0);
                }

            __syncthreads();   // prefetch complete + everyone done reading cur
            cur ^= 1;
        }

        // normalize + store attn[b,s,h,dk] (f16) for out-proj GEMM
#pragma unroll
        for (int no = 0; no < 4; ++no)
#pragma unroll
            for (int r = 0; r < 4; ++r) {
                int row = q0w + lk * 4 + r;
                int col = no * 16 + lrow;
                float v = oacc[no][r] / lstate[r];
                attnB[((size_t)(b * SS) + row) * DD + h * DKK + col] = (f16)v;
            }
    }
}

// ---------------- Out projection GEMM (f32 output) ----------------
__global__ __launch_bounds__(256) void out_gemm(
    const f16* __restrict__ attnB, const f16* __restrict__ wob, float* __restrict__ out)
{
    __shared__ __align__(16) f16 As[2 * 128 * 64];
    __shared__ __align__(16) f16 Bs[2 * 128 * 64];
    const int bm = blockIdx.y * 128, bn = blockIdx.x * 128;
    f32x4 acc[4][4] = {};
    gemm_core(attnB, wob, As, Bs, acc, bm, bn);
    const int tid = threadIdx.x, lane = tid & 63, wid = tid >> 6;
    const int lrow = lane & 15, lk = lane >> 4;
    const int wm = (wid >> 1) * 64, wn = (wid & 1) * 64;
#pragma unroll
    for (int mi = 0; mi < 4; ++mi)
#pragma unroll
        for (int ni = 0; ni < 4; ++ni)
#pragma unroll
            for (int r = 0; r < 4; ++r) {
                int row = bm + wm + mi * 16 + lk * 4 + r;
                int col = bn + wn + ni * 16 + lrow;
                out[(size_t)row * 1024 + col] = acc[mi][ni][r];
            }
}

// ---------------------------------------------------------------------------
extern "C" void kernel_launch(void* const* d_in, const int* in_sizes, int n_in,
                              void* d_out, int out_size, void* d_ws, size_t ws_size,
                              hipStream_t stream) {
    const float* x  = (const float*)d_in[0];
    const float* wq = (const float*)d_in[1];
    const float* wk = (const float*)d_in[2];
    const float* wv = (const float*)d_in[3];
    const float* wo = (const float*)d_in[4];
    float* out = (float*)d_out;

    // workspace layout (f16 elements); attnB aliases xb (xb dead after QKV gemm)
    constexpr size_t NXB = (size_t)MM * DD;   // 8388608
    constexpr size_t NW  = (size_t)DD * DD;   // 1048576
    f16* xb  = (f16*)d_ws;
    f16* wqb = xb  + NXB;
    f16* wkb = wqb + NW;
    f16* wvb = wkb + NW;
    f16* wob = wvb + NW;
    f16* Qr  = wob + NW;
    f16* Kr  = Qr  + NXB;
    f16* Vt  = Kr  + NXB;
    float* ctab = (float*)(Vt + NXB);
    float* stab = ctab + SS * DKK;
    f16* attnB = xb;

    cvt_kernel<<<2048, 256, 0, stream>>>((const float4*)x, (f16x4*)xb, (int)(NXB / 4));
    cvt4_kernel<<<dim3(512, 4), 256, 0, stream>>>((const float4*)wq, (const float4*)wk,
                                                  (const float4*)wv, (const float4*)wo,
                                                  (f16x4*)wqb, (int)(NW / 4));
    rope_tab_kernel<<<(SS * DKK + 255) / 256, 256, 0, stream>>>(ctab, stab);

    qkv_gemm<<<dim3(8, 64, 3), 256, 0, stream>>>(xb, wqb, wkb, wvb, Qr, Kr, Vt, ctab, stab);
    attn_kernel<<<dim3(16, 64), 256, 0, stream>>>(Qr, Kr, Vt, attnB);
    out_gemm<<<dim3(8, 64), 256, 0, stream>>>(attnB, wob, out);
}

// Round 5
// 209.081 us; speedup vs baseline: 1.9752x; 1.1121x over previous
//
#include <hip/hip_runtime.h>

// ---------------------------------------------------------------------------
// MultiHeadSelfAttention: B=4 S=2048 D=1024 H=16 DK=64, RoPE, causal, out-proj
// Round 5 (= round 4 + compile fix): attention restructured:
//   - q-tile 128 rows/block (wave owns 32 q) -> KV re-fetch halved
//   - swapped QK^T (mfma(K,Q)): softmax reduction is lane-local (2 shfl)
//   - exp2-domain softmax (log2e folded into Q scale)
//   - P packed via cvt_pkrtz (native __fp16x2, bit_cast), ds_write_b64
//   - PV = mfma(V,P) -> O^T
// GEMMs unchanged from round 3 (2-phase double-buffer).
// ---------------------------------------------------------------------------

typedef _Float16 f16;
typedef _Float16 f16x4 __attribute__((ext_vector_type(4)));
typedef _Float16 f16x8 __attribute__((ext_vector_type(8)));
typedef float    f32x4 __attribute__((ext_vector_type(4)));
typedef __fp16   h16x2 __attribute__((ext_vector_type(2)));

typedef __attribute__((address_space(1))) void gvoid_t;
typedef __attribute__((address_space(3))) void lvoid_t;

// async global->LDS, 16B per lane; LDS dest = wave-uniform base + lane*16
#define GLD16(g, l) __builtin_amdgcn_global_load_lds( \
    (gvoid_t*)(const void*)(g), (lvoid_t*)(l), 16, 0, 0)

constexpr int BB = 4, SS = 2048, DD = 1024, HH = 16, DKK = 64;
constexpr int MM = BB * SS;  // 8192

// ---------------- f32 -> f16 convert (vectorized) ----------------
__global__ void cvt_kernel(const float4* __restrict__ in, f16x4* __restrict__ out, int n4) {
    int stride = gridDim.x * blockDim.x;
    for (int i = blockIdx.x * blockDim.x + threadIdx.x; i < n4; i += stride) {
        float4 v = in[i];
        f16x4 o;
        o[0] = (f16)v.x; o[1] = (f16)v.y; o[2] = (f16)v.z; o[3] = (f16)v.w;
        out[i] = o;
    }
}

// 4 weight matrices in one launch; dst regions are contiguous in ws
__global__ void cvt4_kernel(const float4* __restrict__ a, const float4* __restrict__ b,
                            const float4* __restrict__ c, const float4* __restrict__ d,
                            f16x4* __restrict__ out, int n4per) {
    const float4* srcs[4] = {a, b, c, d};
    const float4* src = srcs[blockIdx.y];
    f16x4* dst = out + (size_t)blockIdx.y * n4per;
    int stride = gridDim.x * blockDim.x;
    for (int i = blockIdx.x * blockDim.x + threadIdx.x; i < n4per; i += stride) {
        float4 v = src[i];
        f16x4 o;
        o[0] = (f16)v.x; o[1] = (f16)v.y; o[2] = (f16)v.z; o[3] = (f16)v.w;
        dst[i] = o;
    }
}

// ---------------- RoPE tables: ctab/stab[s][dk] = cos/sin(s * invfreq[dk>>1])
__global__ void rope_tab_kernel(float* __restrict__ ctab, float* __restrict__ stab) {
    int idx = blockIdx.x * blockDim.x + threadIdx.x;
    if (idx >= SS * DKK) return;
    int s = idx >> 6, dk = idx & 63, i = dk >> 1;
    float inv = powf(10000.0f, -(float)(2 * i) / (float)DKK);
    float ang = (float)s * inv;
    ctab[idx] = cosf(ang);
    stab[idx] = sinf(ang);
}

// ---------------- GEMM core: C[128x128] tile, A[M][K], B-as-[N][K], K=1024 ---
// BK=64, double-buffered LDS, global_load_lds staging with XOR-swizzled source,
// ONE barrier per K-step, 16x16x32 f16 MFMA, 4 waves 2x2.
__device__ __forceinline__ void gemm_core(
    const f16* __restrict__ A, const f16* __restrict__ Bm,
    f16* As, f16* Bs, f32x4 (&acc)[4][4], int bm, int bn)
{
    const int tid  = threadIdx.x;
    const int lane = tid & 63, wid = tid >> 6;
    const int lrow = lane & 15, lk = lane >> 4;
    const int wm = (wid >> 1) * 64, wn = (wid & 1) * 64;

    const int r_ = tid >> 3, c_ = tid & 7;

    auto STAGE = [&](int buf, int k0) {
#pragma unroll
        for (int j = 0; j < 4; ++j) {
            int r = j * 32 + r_;
            int cs = (c_ ^ (r & 7)) * 8;
            GLD16(A  + (size_t)(bm + r) * 1024 + k0 + cs, As + buf * 8192 + (j * 256 + wid * 64) * 8);
            GLD16(Bm + (size_t)(bn + r) * 1024 + k0 + cs, Bs + buf * 8192 + (j * 256 + wid * 64) * 8);
        }
    };

    auto COMPUTE = [&](int buf) {
        const f16* Ab = As + buf * 8192;
        const f16* Bb = Bs + buf * 8192;
#pragma unroll
        for (int kk = 0; kk < 2; ++kk) {
            f16x8 af[4], bf[4];
#pragma unroll
            for (int mi = 0; mi < 4; ++mi) {
                int row = wm + mi * 16 + lrow;
                af[mi] = *(const f16x8*)&Ab[row * 64 + ((kk * 4 + lk) ^ (row & 7)) * 8];
            }
#pragma unroll
            for (int ni = 0; ni < 4; ++ni) {
                int row = wn + ni * 16 + lrow;
                bf[ni] = *(const f16x8*)&Bb[row * 64 + ((kk * 4 + lk) ^ (row & 7)) * 8];
            }
#pragma unroll
            for (int mi = 0; mi < 4; ++mi)
#pragma unroll
                for (int ni = 0; ni < 4; ++ni)
                    acc[mi][ni] = __builtin_amdgcn_mfma_f32_16x16x32_f16(
                        af[mi], bf[ni], acc[mi][ni], 0, 0, 0);
        }
    };

    STAGE(0, 0);
    __syncthreads();
    int cur = 0;
#pragma unroll 1
    for (int t = 0; t < 15; ++t) {
        STAGE(cur ^ 1, (t + 1) * 64);   // issue next tile FIRST (hides under MFMA)
        COMPUTE(cur);
        __syncthreads();                // drains vmcnt(0): next buffer ready
        cur ^= 1;
    }
    COMPUTE(cur);                       // tail, no prefetch
}

// ---------------- QKV GEMM + RoPE epilogue; z: 0=Q 1=K 2=V ----------------
__global__ __launch_bounds__(256) void qkv_gemm(
    const f16* __restrict__ xb,
    const f16* __restrict__ wqb, const f16* __restrict__ wkb, const f16* __restrict__ wvb,
    f16* __restrict__ Qr, f16* __restrict__ Kr, f16* __restrict__ Vt,
    const float* __restrict__ ctab, const float* __restrict__ stab)
{
    __shared__ __align__(16) f16 As[2 * 128 * 64];
    __shared__ __align__(16) f16 Bs[2 * 128 * 64];
    const int z = blockIdx.z;
    const f16* Bm = (z == 0) ? wqb : (z == 1) ? wkb : wvb;
    const int bm = blockIdx.y * 128, bn = blockIdx.x * 128;
    f32x4 acc[4][4] = {};
    gemm_core(xb, Bm, As, Bs, acc, bm, bn);

    const int tid = threadIdx.x, lane = tid & 63, wid = tid >> 6;
    const int lrow = lane & 15, lk = lane >> 4;
    const int wm = (wid >> 1) * 64, wn = (wid & 1) * 64;

    if (z == 2) {
        // V stored transposed: [b,h,dk,s] so attention stages Vt rows directly
#pragma unroll
        for (int mi = 0; mi < 4; ++mi)
#pragma unroll
            for (int ni = 0; ni < 4; ++ni)
#pragma unroll
                for (int r = 0; r < 4; ++r) {
                    int row = bm + wm + mi * 16 + lk * 4 + r;   // (b,s)
                    int col = bn + wn + ni * 16 + lrow;          // (h,dk)
                    int b = row >> 11, s = row & 2047, h = col >> 6, dk = col & 63;
                    Vt[((size_t)(b * HH + h) * DKK + dk) * SS + s] = (f16)acc[mi][ni][r];
                }
    } else {
        f16* Out = (z == 0) ? Qr : Kr;
        // fold 1/sqrt(DK) AND log2e (attn works in exp2 domain) into Q
        const float scale = (z == 0) ? 0.125f * 1.44269504088896f : 1.0f;
#pragma unroll
        for (int mi = 0; mi < 4; ++mi)
#pragma unroll
            for (int ni = 0; ni < 4; ++ni)
#pragma unroll
                for (int r = 0; r < 4; ++r) {
                    int row = bm + wm + mi * 16 + lk * 4 + r;
                    int col = bn + wn + ni * 16 + lrow;
                    int b = row >> 11, s = row & 2047, h = col >> 6, dk = col & 63;
                    float v = acc[mi][ni][r];
                    float partner = __shfl_xor(v, 1);   // adjacent column (same rows)
                    float cc = ctab[s * DKK + dk], ssn = stab[s * DKK + dk];
                    float rot = (col & 1) ? partner : -partner;
                    float o = (v * cc + rot * ssn) * scale;
                    Out[((size_t)(b * HH + h) * SS + s) * DKK + dk] = (f16)o;
                }
    }
}

// ---------------- Flash attention ----------------
// q-tiles of 128 rows; block px handles q-tiles {px, 15-px} => 34 KV-tiles
// each (perfect causal balance). 4 waves; each wave owns 32 q-rows (mi=0,1).
// Swapped QK^T: sacc[mi][ni][r] = S[kv0+ni*16+lk*4+r][qw+mi*16+lrow] -> the
// softmax row-reduction is 16 in-lane values + shfl_xor(16,32). Softmax in
// exp2 domain (log2e pre-folded into Q). P packed f16 pairs -> ds_write_b64
// into per-wave Ps; PV = mfma(V, P) accumulating O^T[dk][q].
__global__ __launch_bounds__(256, 3) void attn_kernel(
    const f16* __restrict__ Q, const f16* __restrict__ K, const f16* __restrict__ Vt,
    f16* __restrict__ attnB)
{
    __shared__ __align__(16) f16 Ks[2][64 * 64];   // [kv][dk], swizzled chunks
    __shared__ __align__(16) f16 Vs[2][64 * 64];   // [dk][kv], swizzled chunks
    __shared__ __align__(16) f16 Ps[4][32 * 64];   // per-wave P[q_local][kv], swizzled

    const int tid = threadIdx.x, lane = tid & 63, wid = tid >> 6;
    const int lrow = lane & 15, lk = lane >> 4;
    const int bh = blockIdx.y;               // b*16+h
    const int b = bh >> 4, h = bh & 15;
    const int px = blockIdx.x;               // 0..7

    const f16* Qb = Q  + (size_t)bh * SS * DKK;
    const f16* Kb = K  + (size_t)bh * SS * DKK;
    const f16* Vb = Vt + (size_t)bh * DKK * SS;
    f16* PsW = &Ps[wid][0];

    int cur = 0;

    for (int pass = 0; pass < 2; ++pass) {
        const int qt  = pass ? (15 - px) : px;   // q-tile index (128 rows)
        const int qw  = qt * 128 + wid * 32;     // this wave's 32 q-rows
        const int nt  = 2 * qt + 2;              // causal KV tiles of 64

        // Q fragments in registers: qf[mi][kk] = Q[qw+mi*16+lrow][kk*32+lk*8..]
        f16x8 qf[2][2];
#pragma unroll
        for (int mi = 0; mi < 2; ++mi)
#pragma unroll
            for (int kk = 0; kk < 2; ++kk)
                qf[mi][kk] = *(const f16x8*)&Qb[(size_t)(qw + mi * 16 + lrow) * DKK + kk * 32 + lk * 8];

        f32x4 oacc[2][4] = {};
        float mst[2] = {-1e30f, -1e30f}, lst[2] = {0.0f, 0.0f};

        // prologue stage tile 0
#pragma unroll
        for (int j = 0; j < 2; ++j) {
            int ci = j * 256 + tid;
            int r = ci >> 3, c = ci & 7;
            int cs = (c ^ (r & 7)) * 8;
            GLD16(Kb + (size_t)r * DKK + cs, &Ks[cur][(j * 256 + wid * 64) * 8]);
            GLD16(Vb + (size_t)r * SS  + cs, &Vs[cur][(j * 256 + wid * 64) * 8]);
        }
        __syncthreads();

        for (int t = 0; t < nt; ++t) {
            const int kv0 = t * 64;
            // prefetch next KV tile into other buffer
            if (t + 1 < nt) {
                const int kvn = kv0 + 64;
#pragma unroll
                for (int j = 0; j < 2; ++j) {
                    int ci = j * 256 + tid;
                    int r = ci >> 3, c = ci & 7;
                    int cs = (c ^ (r & 7)) * 8;
                    GLD16(Kb + (size_t)(kvn + r) * DKK + cs, &Ks[cur ^ 1][(j * 256 + wid * 64) * 8]);
                    GLD16(Vb + (size_t)r * SS + kvn + cs,    &Vs[cur ^ 1][(j * 256 + wid * 64) * 8]);
                }
            }

            if (kv0 <= qw + 31) {   // wave has at least one unmasked column
                // ---- swapped QK^T: sacc[mi][ni] = S^T chunks ----
                f32x4 sacc[2][4] = {};
#pragma unroll
                for (int kk = 0; kk < 2; ++kk)
#pragma unroll
                    for (int ni = 0; ni < 4; ++ni) {
                        int row = ni * 16 + lrow;
                        f16x8 kf = *(const f16x8*)&Ks[cur][row * 64 + ((kk * 4 + lk) ^ (row & 7)) * 8];
#pragma unroll
                        for (int mi = 0; mi < 2; ++mi)
                            sacc[mi][ni] = __builtin_amdgcn_mfma_f32_16x16x32_f16(
                                kf, qf[mi][kk], sacc[mi][ni], 0, 0, 0);
                    }

                // ---- softmax: lane owns q = qw + mi*16 + lrow ----
#pragma unroll
                for (int mi = 0; mi < 2; ++mi) {
                    const int q  = qw + mi * 16 + lrow;
                    const int ql = mi * 16 + lrow;
                    if (kv0 + 63 > q) {          // causal mask (diag tiles only)
#pragma unroll
                        for (int ni = 0; ni < 4; ++ni)
#pragma unroll
                            for (int r = 0; r < 4; ++r)
                                if (kv0 + ni * 16 + lk * 4 + r > q) sacc[mi][ni][r] = -1e30f;
                    }
                    float m0 = -1e30f;
#pragma unroll
                    for (int ni = 0; ni < 4; ++ni) {
                        float a = fmaxf(sacc[mi][ni][0], sacc[mi][ni][1]);
                        float bx = fmaxf(sacc[mi][ni][2], sacc[mi][ni][3]);
                        m0 = fmaxf(m0, fmaxf(a, bx));
                    }
                    m0 = fmaxf(m0, __shfl_xor(m0, 16));
                    m0 = fmaxf(m0, __shfl_xor(m0, 32));
                    const float mnew  = fmaxf(mst[mi], m0);
                    const float alpha = exp2f(mst[mi] - mnew);
                    mst[mi] = mnew;
                    float rsum = 0.0f;
#pragma unroll
                    for (int ni = 0; ni < 4; ++ni) {
                        float p0 = exp2f(sacc[mi][ni][0] - mnew);
                        float p1 = exp2f(sacc[mi][ni][1] - mnew);
                        float p2 = exp2f(sacc[mi][ni][2] - mnew);
                        float p3 = exp2f(sacc[mi][ni][3] - mnew);
                        rsum += (p0 + p1) + (p2 + p3);
                        h16x2 w0 = __builtin_amdgcn_cvt_pkrtz(p0, p1);
                        h16x2 w1 = __builtin_amdgcn_cvt_pkrtz(p2, p3);
                        f16x4 w;
                        w[0] = (f16)w0[0]; w[1] = (f16)w0[1];
                        w[2] = (f16)w1[0]; w[3] = (f16)w1[1];
                        const int c = ni * 2 + (lk >> 1);
                        *(f16x4*)&PsW[ql * 64 + ((c ^ (ql & 7)) * 8) + (lk & 1) * 4] = w;
                    }
                    rsum += __shfl_xor(rsum, 16);
                    rsum += __shfl_xor(rsum, 32);
                    lst[mi] = lst[mi] * alpha + rsum;
#pragma unroll
                    for (int no = 0; no < 4; ++no)
#pragma unroll
                        for (int r = 0; r < 4; ++r)
                            oacc[mi][no][r] *= alpha;
                }

                // ---- PV: O^T[dk][q] += V^T[dk][kv] x P[q][kv] ----
#pragma unroll
                for (int kk = 0; kk < 2; ++kk) {
                    f16x8 pa[2];
#pragma unroll
                    for (int mi = 0; mi < 2; ++mi) {
                        const int ql = mi * 16 + lrow;
                        pa[mi] = *(const f16x8*)&PsW[ql * 64 + ((kk * 4 + lk) ^ (ql & 7)) * 8];
                    }
#pragma unroll
                    for (int no = 0; no < 4; ++no) {
                        int row = no * 16 + lrow;
                        f16x8 vf = *(const f16x8*)&Vs[cur][row * 64 + ((kk * 4 + lk) ^ (row & 7)) * 8];
#pragma unroll
                        for (int mi = 0; mi < 2; ++mi)
                            oacc[mi][no] = __builtin_amdgcn_mfma_f32_16x16x32_f16(
                                vf, pa[mi], oacc[mi][no], 0, 0, 0);
                    }
                }
            }

            __syncthreads();   // prefetch complete + everyone done reading cur
            cur ^= 1;
        }

        // normalize + store attn[b,s,h,dk] (f16); oacc[mi][no][r] = O[dk][q]
#pragma unroll
        for (int mi = 0; mi < 2; ++mi) {
            const float rl = 1.0f / lst[mi];
            const int q = qw + mi * 16 + lrow;
#pragma unroll
            for (int no = 0; no < 4; ++no) {
                f16x4 w;
#pragma unroll
                for (int r = 0; r < 4; ++r) w[r] = (f16)(oacc[mi][no][r] * rl);
                *(f16x4*)&attnB[((size_t)(b * SS) + q) * DD + h * DKK + no * 16 + lk * 4] = w;
            }
        }
    }
}

// ---------------- Out projection GEMM (f32 output) ----------------
__global__ __launch_bounds__(256) void out_gemm(
    const f16* __restrict__ attnB, const f16* __restrict__ wob, float* __restrict__ out)
{
    __shared__ __align__(16) f16 As[2 * 128 * 64];
    __shared__ __align__(16) f16 Bs[2 * 128 * 64];
    const int bm = blockIdx.y * 128, bn = blockIdx.x * 128;
    f32x4 acc[4][4] = {};
    gemm_core(attnB, wob, As, Bs, acc, bm, bn);
    const int tid = threadIdx.x, lane = tid & 63, wid = tid >> 6;
    const int lrow = lane & 15, lk = lane >> 4;
    const int wm = (wid >> 1) * 64, wn = (wid & 1) * 64;
#pragma unroll
    for (int mi = 0; mi < 4; ++mi)
#pragma unroll
        for (int ni = 0; ni < 4; ++ni)
#pragma unroll
            for (int r = 0; r < 4; ++r) {
                int row = bm + wm + mi * 16 + lk * 4 + r;
                int col = bn + wn + ni * 16 + lrow;
                out[(size_t)row * 1024 + col] = acc[mi][ni][r];
            }
}

// ---------------------------------------------------------------------------
extern "C" void kernel_launch(void* const* d_in, const int* in_sizes, int n_in,
                              void* d_out, int out_size, void* d_ws, size_t ws_size,
                              hipStream_t stream) {
    const float* x  = (const float*)d_in[0];
    const float* wq = (const float*)d_in[1];
    const float* wk = (const float*)d_in[2];
    const float* wv = (const float*)d_in[3];
    const float* wo = (const float*)d_in[4];
    float* out = (float*)d_out;

    // workspace layout (f16 elements); attnB aliases xb (xb dead after QKV gemm)
    constexpr size_t NXB = (size_t)MM * DD;   // 8388608
    constexpr size_t NW  = (size_t)DD * DD;   // 1048576
    f16* xb  = (f16*)d_ws;
    f16* wqb = xb  + NXB;
    f16* wkb = wqb + NW;
    f16* wvb = wkb + NW;
    f16* wob = wvb + NW;
    f16* Qr  = wob + NW;
    f16* Kr  = Qr  + NXB;
    f16* Vt  = Kr  + NXB;
    float* ctab = (float*)(Vt + NXB);
    float* stab = ctab + SS * DKK;
    f16* attnB = xb;

    cvt_kernel<<<2048, 256, 0, stream>>>((const float4*)x, (f16x4*)xb, (int)(NXB / 4));
    cvt4_kernel<<<dim3(512, 4), 256, 0, stream>>>((const float4*)wq, (const float4*)wk,
                                                  (const float4*)wv, (const float4*)wo,
                                                  (f16x4*)wqb, (int)(NW / 4));
    rope_tab_kernel<<<(SS * DKK + 255) / 256, 256, 0, stream>>>(ctab, stab);

    qkv_gemm<<<dim3(8, 64, 3), 256, 0, stream>>>(xb, wqb, wkb, wvb, Qr, Kr, Vt, ctab, stab);
    attn_kernel<<<dim3(8, 64), 256, 0, stream>>>(Qr, Kr, Vt, attnB);
    out_gemm<<<dim3(8, 64), 256, 0, stream>>>(attnB, wob, out);
}